// Round 1
// baseline (10356.367 us; speedup 1.0000x reference)
//
#include <hip/hip_runtime.h>
#include <cstdint>
#include <cstddef>

// ---------------------------------------------------------------------------
// RLSTM: B=32, T=1024, F=256, H=256.
// Key identities: a_rec = a_cur[idx]; gate chunk 4 unused (o_t = i_t);
// x@W is recurrence-free. Phase A precomputes XW[t][b][0:768] and the
// recall-gate x-projection scalar gx[t]. Phase B: 64 persistent WGs, each
// owns 4 h-cols (12 gate cols); per-step cross-WG sync via flag
// release/acquire on hbank[t] (which is also the Hm memory bank).
// ---------------------------------------------------------------------------

#define T_STEPS 1024
#define BSZ 32
#define FDIM 256
#define HDIM 256
#define G3 768           // used gate cols (i,f,g chunks)
#define KWG 64           // phase-B workgroups (<=256 CUs -> co-resident)
#define HS 4             // h-cols per WG
#define JC 12            // gate cols per WG (3 chunks x HS)
#define HPAD 260         // LDS row pad (stride 260 floats: 16B aligned, low conflict)
#define FLAG_STRIDE 16   // uints -> 64B per flag line
#define OMEGA 32

static const size_t AX_BYTES = (size_t)T_STEPS * BSZ * G3 * sizeof(float);        // 96 MiB
static const size_t HB_BYTES = (size_t)(T_STEPS + 1) * BSZ * HDIM * sizeof(float); // 32 MiB
static const size_t GX_BYTES = (size_t)T_STEPS * sizeof(double);

// ------------------------------ Phase A ------------------------------------
// One block per t: XW[t][b][j] = x[b,t,:] . W[:,j], j in [0,768);
// gx[t] = sum_b P_r[b] * (x[b,t,:] . W_r)  (fp64 for idx-rounding fidelity)
__global__ __launch_bounds__(256) void phaseA(const float* __restrict__ x,
                                              const float* __restrict__ W,
                                              const float* __restrict__ W_r,
                                              const float* __restrict__ P_r,
                                              float* __restrict__ AX,
                                              double* __restrict__ gx) {
  const int t = blockIdx.x;
  const int tid = threadIdx.x;
  __shared__ __align__(16) float xs[BSZ][HPAD];
  __shared__ double sred[BSZ];

  for (int i = tid; i < BSZ * FDIM / 4; i += 256) {
    const int b = (i * 4) >> 8;
    const int k = (i * 4) & 255;
    *(float4*)&xs[b][k] = *(const float4*)&x[((size_t)b * T_STEPS + t) * FDIM + k];
  }
  __syncthreads();

  for (int pass = 0; pass < 3; ++pass) {
    const int j = pass * 256 + tid;
    float acc[BSZ];
#pragma unroll
    for (int b = 0; b < BSZ; ++b) acc[b] = 0.f;
    for (int k0 = 0; k0 < FDIM; k0 += 4) {
      const float w0 = W[(size_t)(k0 + 0) * 1024 + j];
      const float w1 = W[(size_t)(k0 + 1) * 1024 + j];
      const float w2 = W[(size_t)(k0 + 2) * 1024 + j];
      const float w3 = W[(size_t)(k0 + 3) * 1024 + j];
#pragma unroll
      for (int b = 0; b < BSZ; ++b) {
        const float4 xv = *(const float4*)&xs[b][k0];  // LDS broadcast
        acc[b] = fmaf(xv.x, w0, acc[b]);
        acc[b] = fmaf(xv.y, w1, acc[b]);
        acc[b] = fmaf(xv.z, w2, acc[b]);
        acc[b] = fmaf(xv.w, w3, acc[b]);
      }
    }
    for (int b = 0; b < BSZ; ++b) AX[((size_t)t * BSZ + b) * G3 + j] = acc[b];
  }

  if (tid < BSZ) {
    double s = 0.0;
    for (int k = 0; k < FDIM; k += 4) {
      const float4 xv = *(const float4*)&xs[tid][k];
      const float4 wv = *(const float4*)&W_r[k];
      s = fma((double)xv.x, (double)wv.x, s);
      s = fma((double)xv.y, (double)wv.y, s);
      s = fma((double)xv.z, (double)wv.z, s);
      s = fma((double)xv.w, (double)wv.w, s);
    }
    sred[tid] = s;
  }
  __syncthreads();
  if (tid == 0) {
    double g = 0.0;
    for (int b = 0; b < BSZ; ++b) g = fma((double)P_r[b], sred[b], g);
    gx[t] = g;
  }
}

// ------------------------------ Phase B ------------------------------------
__global__ __launch_bounds__(256) void phaseB(const float* __restrict__ U,
                                              const float* __restrict__ P,
                                              const float* __restrict__ B_bias,
                                              const float* __restrict__ P_r,
                                              const float* __restrict__ U_r,
                                              float* __restrict__ AX,
                                              float* __restrict__ hbank,
                                              const double* __restrict__ gx,
                                              unsigned int* __restrict__ flags) {
  const int wg = blockIdx.x;
  const int tid = threadIdx.x;

  __shared__ __align__(16) float ULt[JC][HPAD];   // U cols for this WG, k-major
  __shared__ __align__(16) float hL[BSZ][HPAD];   // h_{t-1}
  __shared__ __align__(16) float PL[BSZ][64];
  __shared__ float red[2][BSZ][JC];               // k-split partials of h@U
  __shared__ __align__(16) float acs[JC][36];     // a_cur slice  [jc][b]
  __shared__ __align__(16) float ars[JC][36];     // a_rec slice
  __shared__ float ggs[JC][36];                   // gate pre-activations
  __shared__ __align__(16) float UrL[FDIM];
  __shared__ float PrL[BSZ];
  __shared__ float biasL[JC];
  __shared__ double sbp[BSZ][8];                  // recall-gate partials
  __shared__ int idxS;

  for (int i = tid; i < JC * HDIM; i += 256) {
    const int jc = i >> 8, k = i & 255;
    const int col = (jc >> 2) * HDIM + wg * HS + (jc & 3);
    ULt[jc][k] = U[(size_t)k * 1024 + col];
  }
  for (int i = tid; i < BSZ * 64; i += 256) PL[i >> 6][i & 63] = P[i];
  if (tid < FDIM) UrL[tid] = U_r[tid];
  if (tid < BSZ) PrL[tid] = P_r[tid];
  if (tid < JC) biasL[tid] = B_bias[(tid >> 2) * HDIM + wg * HS + (tid & 3)];

  // (b,jc) item mapping for the 384 = 32x12 slice elements (2 passes)
  const int b0 = tid / JC, jc0 = tid % JC;
  const int col0 = (jc0 >> 2) * HDIM + wg * HS + (jc0 & 3);
  const int i1 = tid + 256;
  const int b1 = i1 / JC, jc1 = i1 % JC;
  const int col1 = (jc1 >> 2) * HDIM + wg * HS + (jc1 & 3);
  const bool act1 = (i1 < BSZ * JC);
  // h@U mapping: kgv in {0,1} halves K, bh = row, jq -> 3 cols
  const int kgv = tid >> 7;
  const int bh = (tid >> 2) & 31;
  const int jq = tid & 3;
  // recall-gate mapping
  const int sb_b = tid & 31, sb_kp = tid >> 5;

  float creg = 0.f;  // c state: threads tid<128 own (b=tid>>2, hc=tid&3)
  __syncthreads();

  for (int t = 0; t < T_STEPS; ++t) {
    // prefetch XW row t for our cols (read-only, safe before sync)
    const size_t a0 = ((size_t)t * BSZ + b0) * G3 + col0;
    const size_t a1 = ((size_t)t * BSZ + b1) * G3 + col1;
    const float xw0 = AX[a0];
    const float xw1 = act1 ? AX[a1] : 0.f;
    double gxt = 0.0;
    if (tid == 0) gxt = gx[t];

    // ---- wait for all WGs to have published h_{t-1} -----------------------
    if (t > 0) {
      if (tid < KWG) {
        int iters = 0;
        while (__hip_atomic_load(&flags[tid * FLAG_STRIDE], __ATOMIC_RELAXED,
                                 __HIP_MEMORY_SCOPE_AGENT) < (unsigned)t) {
          if (++iters > (1 << 16)) break;  // hang guard
        }
      }
      __syncthreads();
      __builtin_amdgcn_fence(__ATOMIC_ACQUIRE, "agent");
    }

    // ---- load h_{t-1} -----------------------------------------------------
    {
      const float* hsrc = hbank + (size_t)t * (BSZ * HDIM);
      for (int i = tid; i < BSZ * HDIM / 4; i += 256) {
        const int b = (i * 4) >> 8, k = (i * 4) & 255;
        *(float4*)&hL[b][k] = *(const float4*)&hsrc[i * 4];
      }
    }
    __syncthreads();

    // ---- recall gate (fp64, bit-identical across WGs) ---------------------
    if (t >= OMEGA) {
      double s = 0.0;
      const int k0b = sb_kp * 32;
      for (int k4 = k0b; k4 < k0b + 32; k4 += 4) {
        const float4 hv = *(const float4*)&hL[sb_b][k4];
        const float4 uv = *(const float4*)&UrL[k4];
        s = fma((double)hv.x, (double)uv.x, s);
        s = fma((double)hv.y, (double)uv.y, s);
        s = fma((double)hv.z, (double)uv.z, s);
        s = fma((double)hv.w, (double)uv.w, s);
      }
      sbp[sb_b][sb_kp] = s;
    }
    __syncthreads();
    if (t >= OMEGA && tid < BSZ) {
      double s = sbp[tid][0];
#pragma unroll
      for (int kp = 1; kp < 8; ++kp) s += sbp[tid][kp];
      sbp[tid][0] = s;
    }
    __syncthreads();
    if (t >= OMEGA && tid == 0) {
      double g = gxt;
      for (int b = 0; b < BSZ; ++b) g = fma((double)PrL[b], sbp[b][0], g);
      const double gate = 1.0 / (1.0 + exp(-g));
      int idx = (int)rint((double)t * gate);  // ties-to-even, matches jnp.round
      const int hi = t - 1;
      if (idx > hi) idx = hi;
      if (idx < 0) idx = 0;
      idxS = idx;
    }
    __syncthreads();

    // ---- prefetch a_rec = a_cur[idx] (our own columns) --------------------
    float arv0 = 0.f, arv1 = 0.f;
    if (t >= OMEGA) {
      const size_t base = (size_t)idxS * BSZ * G3;
      arv0 = AX[base + (size_t)b0 * G3 + col0];
      if (act1) arv1 = AX[base + (size_t)b1 * G3 + col1];
    }

    // ---- h @ U (our 12 cols), K split in halves ---------------------------
    {
      float s0 = 0.f, s1 = 0.f, s2 = 0.f;
      const int kb = kgv * 128;
      for (int k4 = kb; k4 < kb + 128; k4 += 4) {
        const float4 hv = *(const float4*)&hL[bh][k4];
        const float4 u0 = *(const float4*)&ULt[jq * 3 + 0][k4];
        const float4 u1 = *(const float4*)&ULt[jq * 3 + 1][k4];
        const float4 u2 = *(const float4*)&ULt[jq * 3 + 2][k4];
        s0 = fmaf(hv.x, u0.x, s0); s0 = fmaf(hv.y, u0.y, s0);
        s0 = fmaf(hv.z, u0.z, s0); s0 = fmaf(hv.w, u0.w, s0);
        s1 = fmaf(hv.x, u1.x, s1); s1 = fmaf(hv.y, u1.y, s1);
        s1 = fmaf(hv.z, u1.z, s1); s1 = fmaf(hv.w, u1.w, s1);
        s2 = fmaf(hv.x, u2.x, s2); s2 = fmaf(hv.y, u2.y, s2);
        s2 = fmaf(hv.z, u2.z, s2); s2 = fmaf(hv.w, u2.w, s2);
      }
      red[kgv][bh][jq * 3 + 0] = s0;
      red[kgv][bh][jq * 3 + 1] = s1;
      red[kgv][bh][jq * 3 + 2] = s2;
    }
    __syncthreads();

    // ---- a_cur = XW + hU; store to bank; stage a_rec ----------------------
    {
      float v = red[0][b0][jc0] + red[1][b0][jc0] + xw0;
      AX[a0] = v;
      acs[jc0][b0] = v;
      ars[jc0][b0] = (t < OMEGA) ? v : arv0;
    }
    if (act1) {
      float v = red[0][b1][jc1] + red[1][b1][jc1] + xw1;
      AX[a1] = v;
      acs[jc1][b1] = v;
      ars[jc1][b1] = (t < OMEGA) ? v : arv1;
    }
    __syncthreads();

    // ---- gates = P @ [a_cur; a_rec] + bias --------------------------------
    {
      float g = biasL[jc0];
#pragma unroll
      for (int b4 = 0; b4 < BSZ; b4 += 4) {
        const float4 pv = *(const float4*)&PL[b0][b4];
        const float4 av = *(const float4*)&acs[jc0][b4];
        g = fmaf(pv.x, av.x, g); g = fmaf(pv.y, av.y, g);
        g = fmaf(pv.z, av.z, g); g = fmaf(pv.w, av.w, g);
      }
#pragma unroll
      for (int b4 = 0; b4 < BSZ; b4 += 4) {
        const float4 pv = *(const float4*)&PL[b0][BSZ + b4];
        const float4 av = *(const float4*)&ars[jc0][b4];
        g = fmaf(pv.x, av.x, g); g = fmaf(pv.y, av.y, g);
        g = fmaf(pv.z, av.z, g); g = fmaf(pv.w, av.w, g);
      }
      ggs[jc0][b0] = g;
    }
    if (act1) {
      float g = biasL[jc1];
#pragma unroll
      for (int b4 = 0; b4 < BSZ; b4 += 4) {
        const float4 pv = *(const float4*)&PL[b1][b4];
        const float4 av = *(const float4*)&acs[jc1][b4];
        g = fmaf(pv.x, av.x, g); g = fmaf(pv.y, av.y, g);
        g = fmaf(pv.z, av.z, g); g = fmaf(pv.w, av.w, g);
      }
#pragma unroll
      for (int b4 = 0; b4 < BSZ; b4 += 4) {
        const float4 pv = *(const float4*)&PL[b1][BSZ + b4];
        const float4 av = *(const float4*)&ars[jc1][b4];
        g = fmaf(pv.x, av.x, g); g = fmaf(pv.y, av.y, g);
        g = fmaf(pv.z, av.z, g); g = fmaf(pv.w, av.w, g);
      }
      ggs[jc1][b1] = g;
    }
    __syncthreads();

    // ---- LSTM update + publish h_t ---------------------------------------
    if (tid < BSZ * HS) {
      const int b = tid >> 2, hc = tid & 3;
      const float gi = ggs[hc][b];
      const float gf = ggs[4 + hc][b];
      const float gg = ggs[8 + hc][b];
      const float iv = 1.f / (1.f + expf(-gi));
      const float fv = 1.f / (1.f + expf(-gf));
      const float gv = tanhf(gg);
      creg = fmaf(fv, creg, iv * gv);
      const float hv = iv * tanhf(creg);  // o_t = i_t (faithful to source)
      hbank[(size_t)(t + 1) * (BSZ * HDIM) + (size_t)b * HDIM + wg * HS + hc] = hv;
    }
    __syncthreads();  // drain all hbank stores (vmcnt) before release
    if (tid == 0) {
      __builtin_amdgcn_fence(__ATOMIC_RELEASE, "agent");
      __hip_atomic_store(&flags[wg * FLAG_STRIDE], (unsigned)(t + 1),
                         __ATOMIC_RELAXED, __HIP_MEMORY_SCOPE_AGENT);
    }
  }
}

// ------------------------------ Output -------------------------------------
__global__ void outK(const float* __restrict__ hbank, const float* __restrict__ W_out,
                     const float* __restrict__ b_out, float* __restrict__ out) {
  const int b = threadIdx.x;
  if (b < BSZ) {
    const float* h = hbank + (size_t)T_STEPS * BSZ * HDIM + (size_t)b * HDIM;
    float s = 0.f;
    for (int k = 0; k < HDIM; k += 4) {
      const float4 hv = *(const float4*)&h[k];
      const float4 wv = *(const float4*)&W_out[k];
      s = fmaf(hv.x, wv.x, s); s = fmaf(hv.y, wv.y, s);
      s = fmaf(hv.z, wv.z, s); s = fmaf(hv.w, wv.w, s);
    }
    out[b] = s + b_out[0];
  }
}

// ------------------------------ Launch -------------------------------------
extern "C" void kernel_launch(void* const* d_in, const int* in_sizes, int n_in,
                              void* d_out, int out_size, void* d_ws, size_t ws_size,
                              hipStream_t stream) {
  const float* x      = (const float*)d_in[0];
  const float* W      = (const float*)d_in[1];
  const float* U      = (const float*)d_in[2];
  const float* P      = (const float*)d_in[3];
  const float* B_bias = (const float*)d_in[4];
  const float* W_r    = (const float*)d_in[5];
  const float* P_r    = (const float*)d_in[6];
  const float* U_r    = (const float*)d_in[7];
  const float* W_out  = (const float*)d_in[8];
  const float* b_out  = (const float*)d_in[9];

  char* ws = (char*)d_ws;
  float*    AX    = (float*)ws;
  float*    hbank = (float*)(ws + AX_BYTES);
  double*   gx    = (double*)(ws + AX_BYTES + HB_BYTES);
  unsigned* flags = (unsigned*)(ws + AX_BYTES + HB_BYTES + GX_BYTES);

  hipMemsetAsync(hbank, 0, (size_t)BSZ * HDIM * sizeof(float), stream);  // h0 = 0
  hipMemsetAsync(flags, 0, (size_t)KWG * FLAG_STRIDE * sizeof(unsigned), stream);

  phaseA<<<T_STEPS, 256, 0, stream>>>(x, W, W_r, P_r, AX, gx);
  phaseB<<<KWG, 256, 0, stream>>>(U, P, B_bias, P_r, U_r, AX, hbank, gx, flags);
  outK<<<1, 64, 0, stream>>>(hbank, W_out, b_out, (float*)d_out);
}